// Round 2
// 308.364 us; speedup vs baseline: 1.3680x; 1.3680x over previous
//
#include <hip/hip_runtime.h>
#include <math.h>

// QuaternionAttention B=4, L=S=2048, H=8, E=64, M=4 (fp32 in/out).
// Round 10 = round 9 resubmit (broker infra error, no kernel signal) with one
// fix: the folded softmax scale constant was 0.04507592944, corrected to
// log2(e)/32 = 0.04508422.
//
// Structure (round 9): trig-folded-operand rewrite.
//   score(l,s) = sum_{m,e} Q_rot(l,m,e) * K_rot(s,m,e) / 32   (K-dim = M*E = 256)
// Q_rot built ONCE per block directly into MFMA A-frags (trig + log2e/32 scale
// folded in, 8 x f16x8 regs). K_rot built per tile into LDS (32KB, 16B-chunk
// XOR swizzle) by 256 threads from register-pipelined global loads. This
// removes the 336-op/lane fp32 ABCD combine of round 8 entirely; MFMA count
// unchanged (32 QK + 8 PV per wave-tile). Also: base-2 online softmax
// (v_exp native), P-store swizzle fixed with row-bit-3 XOR (was 4-way bank
// conflict), next-tile K/trig/V loads issued before the barrier (latency
// hidden under QK/softmax/PV).

#define B_ 4
#define L_ 2048
#define S_ 2048
#define H_ 8
#define E_ 64
#define M_ 4
#define NTH 256

typedef _Float16 f16x4 __attribute__((ext_vector_type(4)));
typedef _Float16 f16x8 __attribute__((ext_vector_type(8)));
typedef __fp16 fp16x2 __attribute__((ext_vector_type(2)));   // cvt_pkrtz return type
typedef float f32x4 __attribute__((ext_vector_type(4)));

union H4U { f16x4 h; fp16x2 p[2]; };
union H8U { f16x8 h; fp16x2 p[4]; };
union F4U { float4 v; float f[4]; };

__device__ __forceinline__ f16x4 cvt4(float x, float y, float z, float w) {
    H4U r;
    r.p[0] = __builtin_amdgcn_cvt_pkrtz(x, y);
    r.p[1] = __builtin_amdgcn_cvt_pkrtz(z, w);
    return r.h;
}
__device__ __forceinline__ f16x8 cvt8(const float* v) {
    H8U r;
#pragma unroll
    for (int i = 0; i < 4; ++i) r.p[i] = __builtin_amdgcn_cvt_pkrtz(v[2 * i], v[2 * i + 1]);
    return r.h;
}

__global__ __launch_bounds__(NTH)
void qattn3(const float* __restrict__ qp, const float* __restrict__ kp,
            const float* __restrict__ vp,
            const float* __restrict__ qo, const float* __restrict__ qt,
            const float* __restrict__ ko, const float* __restrict__ ktt,
            float* __restrict__ out)
{
    const int l0 = blockIdx.x * 64;
    const int h  = blockIdx.y;
    const int b  = blockIdx.z;
    const int t  = threadIdx.x;
    const int wv   = t >> 6;
    const int lane = t & 63;
    const int quad = lane >> 4;
    const int nn   = lane & 15;

    // kd = m*64 + c*16 + i  (c = quaternion component, i = e within 16)
    // chunk = kd>>3 (16B), swizzled: low 3 bits ^= (key&7). Writes and reads
    // both land 8 distinct bank-groups per 8-lane group -> conflict-free.
    __shared__ __align__(16) _Float16 krot[64][256];   // 32KB K_rot tile
    __shared__ __align__(16) _Float16 vts[64][64];     // V^T [e][key]
    __shared__ __align__(16) _Float16 pss[64][64];     // P [row][key], bit3-fixed swizzle
    __shared__ float qtrc[64][4], qtrs[64][4];

    const float* kb0 = kp  + ((size_t)((b * S_) * H_ + h)) * E_;
    const float* vb0 = vp  + ((size_t)((b * S_) * H_ + h)) * E_;
    const float* kob = ko  + ((size_t)((b * S_) * H_ + h)) * M_;
    const float* ktb = ktt + ((size_t)((b * S_) * H_ + h)) * M_;

    const int key_r = t >> 2;      // K_rot build: this thread's key
    const int cc    = t & 3;       //              this thread's component
    const int swz   = key_r & 7;
    const int kg = t >> 4;         // V transpose: key group (4 keys)
    const int eg = t & 15;         //              e group (4 e's)

    // ---- register pipeline: next tile's K slices, trig, V rows ----
    F4U kA[4], kB[4], omR, thR, vv[4];
    auto LOAD = [&](int s0) {
        const float* kr = kb0 + (size_t)(s0 + key_r) * (H_ * E_);
#pragma unroll
        for (int j = 0; j < 4; ++j) {
            kA[j].v = *(const float4*)(kr + cc * 16 + j * 4);        // a = k[cc]
            kB[j].v = *(const float4*)(kr + (cc ^ 2) * 16 + j * 4);  // b = k[cc^2]
        }
        omR.v = *(const float4*)(kob + (size_t)(s0 + key_r) * (H_ * M_));
        thR.v = *(const float4*)(ktb + (size_t)(s0 + key_r) * (H_ * M_));
#pragma unroll
        for (int j = 0; j < 4; ++j)
            vv[j].v = *(const float4*)(vb0 + (size_t)(s0 + kg * 4 + j) * (H_ * E_) + eg * 4);
    };
    LOAD(0);   // tile-0 loads fly during Q_rot construction

    // ---- build Q_rot A-fragments once per block (scale log2(e)/32 folded) ----
    // A-frag ks (K=32 step): kd = ks*32 + quad*8 + j  ->  m=ks>>1,
    // c = (ks&1)*2 + (quad>>1), i = (quad&1)*8 + j.
    f16x8 qa[8];
    {
        float (*qstage)[68] = reinterpret_cast<float (*)[68]>(&krot[0][0]); // 17.4KB overlay
        const float* qb = qp + ((size_t)((b * L_ + l0) * H_ + h)) * E_;
#pragma unroll
        for (int i = 0; i < 4; ++i) {
            int idx = t + NTH * i;
            int row = idx >> 4, c16 = idx & 15;
            *(float4*)&qstage[row][c16 * 4] =
                *(const float4*)(qb + (size_t)row * (H_ * E_) + c16 * 4);
        }
        {
            int row = t >> 2, m = t & 3;
            size_t off = (size_t)((b * L_ + l0 + row) * H_ + h) * M_ + m;
            float ang = qo[off] * ((float)(l0 + row) * (1.0f / L_)) + qt[off];
            float sv, cv;
            __sincosf(ang, &sv, &cv);
            qtrc[row][m] = cv;
            qtrs[row][m] = sv;
        }
        __syncthreads();
        const int row = wv * 16 + nn;   // A-frag row = lane&15
        const int i0 = (quad & 1) * 8;
        float sl0[8], sl1[8], sl2[8], sl3[8];
        *(float4*)&sl0[0] = *(float4*)&qstage[row][ 0 + i0];
        *(float4*)&sl0[4] = *(float4*)&qstage[row][ 4 + i0];
        *(float4*)&sl1[0] = *(float4*)&qstage[row][16 + i0];
        *(float4*)&sl1[4] = *(float4*)&qstage[row][20 + i0];
        *(float4*)&sl2[0] = *(float4*)&qstage[row][32 + i0];
        *(float4*)&sl2[4] = *(float4*)&qstage[row][36 + i0];
        *(float4*)&sl3[0] = *(float4*)&qstage[row][48 + i0];
        *(float4*)&sl3[4] = *(float4*)&qstage[row][52 + i0];
        // even ks -> c = quad>>1 (0 or 1); odd ks -> c+2.
        // Q signs: c0:-, c1:+, c2:+, c3:-   (b = q[c^1])
        const bool hiC = (quad & 2) != 0;
        float aE[8], bE[8], aO[8], bO[8];
#pragma unroll
        for (int j = 0; j < 8; ++j) {
            aE[j] = hiC ? sl1[j] : sl0[j];
            bE[j] = hiC ? sl0[j] : sl1[j];
            aO[j] = hiC ? sl3[j] : sl2[j];
            bO[j] = hiC ? sl2[j] : sl3[j];
        }
        F4U qc4, qs4;
        qc4.v = *(float4*)&qtrc[row][0];
        qs4.v = *(float4*)&qtrs[row][0];
        const float SC = 0.04508422017f;   // log2(e)/32, correctly rounded
#pragma unroll
        for (int m = 0; m < 4; ++m) {
            float cm = qc4.f[m] * SC;
            float sm = qs4.f[m] * SC;
            float sE = hiC ? sm : -sm;     // c=1:+  c=0:-
            float vE[8], vO[8];
#pragma unroll
            for (int j = 0; j < 8; ++j) {
                vE[j] = fmaf(bE[j], sE, aE[j] * cm);
                vO[j] = fmaf(bO[j], -sE, aO[j] * cm);   // c=2:+  c=3:-
            }
            qa[2 * m]     = cvt8(vE);
            qa[2 * m + 1] = cvt8(vO);
        }
        __syncthreads();   // qstage (krot alias) now free
    }

    f32x4 Oacc[4] = {{0,0,0,0},{0,0,0,0},{0,0,0,0},{0,0,0,0}};
    float mrow[4] = {-1e30f,-1e30f,-1e30f,-1e30f};
    float lrow[4] = {0.f,0.f,0.f,0.f};
    const int xr0 = nn & 7;

    for (int s0 = 0; s0 < S_; s0 += 64) {
        // ---- K_rot build from pipeline regs (K signs: c0:-, c1:-, c2:+, c3:+) ----
        {
            float af[16], bf[16];
#pragma unroll
            for (int j = 0; j < 4; ++j)
#pragma unroll
                for (int i2 = 0; i2 < 4; ++i2) {
                    af[j * 4 + i2] = kA[j].f[i2];
                    bf[j * 4 + i2] = kB[j].f[i2];
                }
            float posk = (float)(s0 + key_r) * (1.0f / S_);
            float kcv[4], ksv[4];
#pragma unroll
            for (int m = 0; m < 4; ++m) {
                float ang = omR.f[m] * posk + thR.f[m];
                __sincosf(ang, &ksv[m], &kcv[m]);
            }
            const float sgn = (cc >= 2) ? 1.f : -1.f;
#pragma unroll
            for (int m = 0; m < 4; ++m) {
                float cm = kcv[m], sm = ksv[m] * sgn;
                float vals[16];
#pragma unroll
                for (int i = 0; i < 16; ++i)
                    vals[i] = fmaf(bf[i], sm, af[i] * cm);
                int ch0 = (m * 8) | ((cc * 2 + 0) ^ swz);
                int ch1 = (m * 8) | ((cc * 2 + 1) ^ swz);
                *(f16x8*)&krot[key_r][ch0 * 8] = cvt8(&vals[0]);
                *(f16x8*)&krot[key_r][ch1 * 8] = cvt8(&vals[8]);
            }
        }
        // ---- V^T staging (4x4 register-block transpose) ----
        {
#pragma unroll
            for (int e = 0; e < 4; ++e) {
                int row = eg * 4 + e;
                int ch = ((kg >> 1) ^ (row & 7));
                *(f16x4*)&vts[row][ch * 8 + (kg & 1) * 4] =
                    cvt4(vv[0].f[e], vv[1].f[e], vv[2].f[e], vv[3].f[e]);
            }
        }
        if (s0 + 64 < S_) LOAD(s0 + 64);   // next tile in flight across the compute phase
        __syncthreads();

        // ---- QK^T: one K=256 MFMA chain, scores come out pre-scaled ----
        float sc[4][4];
#pragma unroll
        for (int kt2 = 0; kt2 < 4; ++kt2) {
            const int keyb = kt2 * 16 + nn;
            f32x4 acc = {0, 0, 0, 0};
#pragma unroll
            for (int ks = 0; ks < 8; ++ks) {
                f16x8 bK = *(const f16x8*)&krot[keyb][((ks * 4 + quad) ^ xr0) * 8];
                acc = __builtin_amdgcn_mfma_f32_16x16x32_f16(qa[ks], bK, acc, 0, 0, 0);
            }
#pragma unroll
            for (int r = 0; r < 4; ++r) sc[kt2][r] = acc[r];
        }

        // ---- online softmax in base 2, P write (bit3-fixed swizzle) ----
#pragma unroll
        for (int r = 0; r < 4; ++r) {
            float tm = fmaxf(fmaxf(sc[0][r], sc[1][r]), fmaxf(sc[2][r], sc[3][r]));
            tm = fmaxf(tm, __shfl_xor(tm, 1));
            tm = fmaxf(tm, __shfl_xor(tm, 2));
            tm = fmaxf(tm, __shfl_xor(tm, 4));
            tm = fmaxf(tm, __shfl_xor(tm, 8));
            float mnew  = fmaxf(mrow[r], tm);
            float alpha = __builtin_amdgcn_exp2f(mrow[r] - mnew);
            int row = wv * 16 + quad * 4 + r;
            int sw = (row & 7) ^ ((row >> 3) & 1);
            float psum = 0.f;
#pragma unroll
            for (int kt2 = 0; kt2 < 4; ++kt2) {
                float p = __builtin_amdgcn_exp2f(sc[kt2][r] - mnew);
                psum += p;
                int key = kt2 * 16 + nn;
                int ch = (key >> 3) ^ sw;
                pss[row][ch * 8 + (key & 7)] = (_Float16)p;
            }
            psum += __shfl_xor(psum, 1);
            psum += __shfl_xor(psum, 2);
            psum += __shfl_xor(psum, 4);
            psum += __shfl_xor(psum, 8);
            lrow[r] = lrow[r] * alpha + psum;
            mrow[r] = mnew;
            Oacc[0][r] *= alpha; Oacc[1][r] *= alpha;
            Oacc[2][r] *= alpha; Oacc[3][r] *= alpha;
        }

        // ---- PV (wave-local P round-trip, no barrier needed) ----
        {
            const int prow = wv * 16 + nn;
            const int swp = (prow & 7) ^ ((prow >> 3) & 1);
#pragma unroll
            for (int ks2 = 0; ks2 < 2; ++ks2) {
                f16x8 pf = *(const f16x8*)&pss[prow][((quad + 4 * ks2) ^ swp) * 8];
#pragma unroll
                for (int et = 0; et < 4; ++et) {
                    int e = et * 16 + nn;
                    f16x8 vf = *(const f16x8*)&vts[e][((quad + 4 * ks2) ^ (e & 7)) * 8];
                    Oacc[et] = __builtin_amdgcn_mfma_f32_16x16x32_f16(pf, vf, Oacc[et], 0, 0, 0);
                }
            }
        }
        __syncthreads();   // protect krot/vts before next build
    }

    // ---- epilogue ----
    float* ob = out + ((size_t)((b * L_ + l0) * H_ + h)) * E_;
#pragma unroll
    for (int r = 0; r < 4; ++r) {
        float inv = 1.0f / lrow[r];
        int row = wv * 16 + quad * 4 + r;
#pragma unroll
        for (int et = 0; et < 4; ++et)
            ob[(size_t)row * (H_ * E_) + et * 16 + nn] = Oacc[et][r] * inv;
    }
}

extern "C" void kernel_launch(void* const* d_in, const int* in_sizes, int n_in,
                              void* d_out, int out_size, void* d_ws, size_t ws_size,
                              hipStream_t stream) {
    const float* qp = (const float*)d_in[0];
    const float* kp = (const float*)d_in[1];
    const float* vp = (const float*)d_in[2];
    const float* qo = (const float*)d_in[3];
    const float* qt = (const float*)d_in[4];
    const float* ko = (const float*)d_in[5];
    const float* kt = (const float*)d_in[6];
    float* out = (float*)d_out;

    dim3 grid(L_ / 64, H_, B_);
    qattn3<<<grid, dim3(NTH), 0, stream>>>(qp, kp, vp, qo, qt, ko, kt, out);
}